// Round 8
// baseline (148.614 us; speedup 1.0000x reference)
//
#include <hip/hip_runtime.h>
#include <cstdint>
#include <cstddef>

#define D 64

typedef float    f32x4 __attribute__((ext_vector_type(4)));
typedef float    f32x2 __attribute__((ext_vector_type(2)));
typedef short    s16x8 __attribute__((ext_vector_type(8)));
typedef uint32_t u32x4 __attribute__((ext_vector_type(4)));

// round-to-nearest-even fp32 -> bf16 (bits in low 16)
__device__ __forceinline__ uint32_t rne_bf16(float f) {
    uint32_t x = __float_as_uint(f);
    return (x + 0x7fffu + ((x >> 16) & 1u)) >> 16;
}
__device__ __forceinline__ float bf16lo(uint32_t u) { return __uint_as_float(u << 16); }
__device__ __forceinline__ float bf16hi(uint32_t u) { return __uint_as_float(u & 0xffff0000u); }

// Kernel 1: Xh = packed bf16(X). u32 t of a row packs features (2t, 2t+1).
__global__ __launch_bounds__(256) void cast_kernel(
    const float* __restrict__ X, uint32_t* __restrict__ Xh, long n4)
{
    long i = (long)blockIdx.x * blockDim.x + threadIdx.x;
    const long stride = (long)gridDim.x * blockDim.x;
    for (; i < n4; i += stride) {
        f32x4 v = __builtin_nontemporal_load((const f32x4*)X + i);
        uint2 o;
        o.x = rne_bf16(v.x) | (rne_bf16(v.y) << 16);
        o.y = rne_bf16(v.z) | (rne_bf16(v.w) << 16);
        ((uint2*)Xh)[i] = o;
    }
}

__device__ __forceinline__ void acc_row(f32x2 acc[4], const u32x4 u) {
#pragma unroll
    for (int k = 0; k < 4; ++k) {
        f32x2 v;
        v.x = bf16lo(u[k]);
        v.y = bf16hi(u[k]);
        acc[k] += v;          // v_pk_add_f32
    }
}

// Kernel 2: Agg[r] = bf16( sum_{e in row r} Xh[ci[e]] ).
// ONE row per wave, single uniform predicated path (no remainder ladder).
// o = lane>>3 (edge slot), p = lane&7 (feature octet; uint4 = 8 bf16).
// Per 64-edge block: stage A (edges 0..31) always, stage B (32..63) under a
// wave-uniform branch. Within a stage: 4 clamped idx loads issue first, then
// 4 exec-predicated row gathers (zero-filled when inactive), then
// unconditional accumulate -> no idx/gather issue interleaving, 4 gathers in
// flight.
__global__ __launch_bounds__(256) void gather4_kernel(
    const uint32_t* __restrict__ Xh, const int* __restrict__ rp,
    const int* __restrict__ ci, uint32_t* __restrict__ Agg, int n_nodes)
{
    const int lane = threadIdx.x & 63;
    const int o = lane >> 3;
    const int p = lane & 7;
    const int row = (int)((blockIdx.x * blockDim.x + threadIdx.x) >> 6);
    if (row >= n_nodes) return;

    const int e0 = rp[row];
    const int e1 = rp[row + 1];

    f32x2 accA[4] = {{0.f,0.f},{0.f,0.f},{0.f,0.f},{0.f,0.f}};
    f32x2 accB[4] = {{0.f,0.f},{0.f,0.f},{0.f,0.f},{0.f,0.f}};

    for (int e = e0; e < e1; e += 64) {
        const int rem = e1 - e;          // wave-uniform
        const int last = e1 - 1;
        {   // stage A: edges e .. e+31
            // clamped unpredicated idx loads (always in-bounds)
            const int i0 = ci[min(e + o,      last)];
            const int i1 = ci[min(e + 8 + o,  last)];
            const int i2 = ci[min(e + 16 + o, last)];
            const int i3 = ci[min(e + 24 + o, last)];
            u32x4 u0 = {0,0,0,0}, u1 = {0,0,0,0}, u2 = {0,0,0,0}, u3 = {0,0,0,0};
            if (o < rem)      u0 = *(const u32x4*)(Xh + (size_t)i0 * 32 + p * 4);
            if (8 + o < rem)  u1 = *(const u32x4*)(Xh + (size_t)i1 * 32 + p * 4);
            if (16 + o < rem) u2 = *(const u32x4*)(Xh + (size_t)i2 * 32 + p * 4);
            if (24 + o < rem) u3 = *(const u32x4*)(Xh + (size_t)i3 * 32 + p * 4);
            acc_row(accA, u0); acc_row(accB, u1);
            acc_row(accA, u2); acc_row(accB, u3);
        }
        if (rem > 32) {  // stage B: edges e+32 .. e+63 (wave-uniform skip)
            const int i0 = ci[min(e + 32 + o, last)];
            const int i1 = ci[min(e + 40 + o, last)];
            const int i2 = ci[min(e + 48 + o, last)];
            const int i3 = ci[min(e + 56 + o, last)];
            u32x4 u0 = {0,0,0,0}, u1 = {0,0,0,0}, u2 = {0,0,0,0}, u3 = {0,0,0,0};
            if (32 + o < rem) u0 = *(const u32x4*)(Xh + (size_t)i0 * 32 + p * 4);
            if (40 + o < rem) u1 = *(const u32x4*)(Xh + (size_t)i1 * 32 + p * 4);
            if (48 + o < rem) u2 = *(const u32x4*)(Xh + (size_t)i2 * 32 + p * 4);
            if (56 + o < rem) u3 = *(const u32x4*)(Xh + (size_t)i3 * 32 + p * 4);
            acc_row(accA, u0); acc_row(accB, u1);
            acc_row(accA, u2); acc_row(accB, u3);
        }
    }

    // reduce across the 8 edge slots (lane bits 3..5); all lanes get sums
#pragma unroll
    for (int k = 0; k < 4; ++k) {
        f32x2 v = accA[k] + accB[k];
        v.x += __shfl_xor(v.x, 8, 64);  v.y += __shfl_xor(v.y, 8, 64);
        v.x += __shfl_xor(v.x, 16, 64); v.y += __shfl_xor(v.y, 16, 64);
        v.x += __shfl_xor(v.x, 32, 64); v.y += __shfl_xor(v.y, 32, 64);
        accA[k] = v;
    }
    if (lane < 8) {   // lanes 0..7: o==0, p=0..7
        u32x4 w;
#pragma unroll
        for (int k = 0; k < 4; ++k)
            w[k] = rne_bf16(accA[k].x) | (rne_bf16(accA[k].y) << 16);
        *(u32x4*)(Agg + (size_t)row * 32 + p * 4) = w;  // 8 lanes x 16B = 128B
    }
}

// Kernel 3: out = Agg(bf16) @ W via mfma_f32_16x16x32_bf16.
// One wave per 16-row tile (grid-strided). B-frags (W) in VGPRs per wave.
// A-frag: A[m=lane&15][k=q*8+j]; B-frag: B[k=q*8+j][n=lane&15];
// C/D: col=lane&15, row=q*4+reg  (q = lane>>4).
__global__ __launch_bounds__(256) void agg_gemm_kernel(
    const uint32_t* __restrict__ Agg, const float* __restrict__ W,
    float* __restrict__ out, int n_nodes)
{
    const int lane = threadIdx.x & 63;
    const int n = lane & 15;
    const int q = lane >> 4;

    s16x8 Bf[4][2];
#pragma unroll
    for (int c = 0; c < 4; ++c)
#pragma unroll
        for (int kb = 0; kb < 2; ++kb) {
            s16x8 bfr;
#pragma unroll
            for (int j = 0; j < 8; ++j) {
                const int k = kb * 32 + q * 8 + j;
                bfr[j] = (short)rne_bf16(W[k * D + c * 16 + n]);
            }
            Bf[c][kb] = bfr;
        }

    const int n_tiles = (n_nodes + 15) / 16;
    const int gwave = (int)((blockIdx.x * blockDim.x + threadIdx.x) >> 6);
    const int nwaves = (int)((gridDim.x * blockDim.x) >> 6);

    for (int t = gwave; t < n_tiles; t += nwaves) {
        const int m0 = t * 16;
        int arow = m0 + n;
        if (arow >= n_nodes) arow = n_nodes - 1;  // clamp (tail tile)
        const s16x8 A0 = *(const s16x8*)(Agg + (size_t)arow * 32 + q * 4);
        const s16x8 A1 = *(const s16x8*)(Agg + (size_t)arow * 32 + 16 + q * 4);

        f32x4 acc[4];
#pragma unroll
        for (int c = 0; c < 4; ++c) {
            f32x4 z = {0.f, 0.f, 0.f, 0.f};
            z = __builtin_amdgcn_mfma_f32_16x16x32_bf16(A0, Bf[c][0], z, 0, 0, 0);
            z = __builtin_amdgcn_mfma_f32_16x16x32_bf16(A1, Bf[c][1], z, 0, 0, 0);
            acc[c] = z;
        }
#pragma unroll
        for (int r = 0; r < 4; ++r) {
            const int ro = m0 + q * 4 + r;
            if (ro < n_nodes) {
#pragma unroll
                for (int c = 0; c < 4; ++c)
                    out[(size_t)ro * D + c * 16 + n] = acc[c][r];
            }
        }
    }
}

// Fallback if ws can't hold Xh+Agg: fused per-row aggregate + shfl GEMM.
__global__ __launch_bounds__(256) void fused_kernel(
    const float* __restrict__ X, const float* __restrict__ W,
    const int* __restrict__ rp, const int* __restrict__ ci,
    float* __restrict__ out, int n_nodes)
{
    __shared__ float Wl[D * D];
    for (int i = threadIdx.x; i < D * D; i += 256) Wl[i] = W[i];
    __syncthreads();

    const int lane = threadIdx.x & 63;
    const int gwave = (int)((blockIdx.x * blockDim.x + threadIdx.x) >> 6);
    const int nwaves = (int)((gridDim.x * blockDim.x) >> 6);

    for (int row = gwave; row < n_nodes; row += nwaves) {
        int e0 = rp[row];
        int e1 = rp[row + 1];
        float acc = 0.f;
        for (int e = e0; e < e1; ++e) acc += X[ci[e] * D + lane];
        float sum = 0.f;
#pragma unroll
        for (int d = 0; d < D; ++d) {
            float a = __shfl(acc, d, 64);
            sum += a * Wl[d * D + lane];
        }
        out[row * D + lane] = sum;
    }
}

extern "C" void kernel_launch(void* const* d_in, const int* in_sizes, int n_in,
                              void* d_out, int out_size, void* d_ws, size_t ws_size,
                              hipStream_t stream)
{
    const float* X  = (const float*)d_in[0];   // [n, 64]
    const float* W  = (const float*)d_in[1];   // [64, 64]
    const int*   rp = (const int*)d_in[2];     // [n+1]
    const int*   ci = (const int*)d_in[3];     // [n_edges]
    float* out = (float*)d_out;

    const int n_nodes = in_sizes[2] - 1;
    const size_t row_bytes = 32 * sizeof(uint32_t);           // 128 B bf16 row
    const size_t need = 2 * (size_t)n_nodes * row_bytes;      // Xh + Agg

    if (ws_size >= need) {
        uint32_t* Xh  = (uint32_t*)d_ws;
        uint32_t* Agg = (uint32_t*)((char*)d_ws + (size_t)n_nodes * row_bytes);

        const long n4 = (long)n_nodes * (D / 4);
        int cast_blocks = (int)((n4 + 255) / 256);
        if (cast_blocks > 6400) cast_blocks = 6400;
        cast_kernel<<<cast_blocks, 256, 0, stream>>>(X, Xh, n4);

        const int gather_blocks = (n_nodes + 3) / 4;  // 1 row/wave, 4 waves/block
        gather4_kernel<<<gather_blocks, 256, 0, stream>>>(Xh, rp, ci, Agg, n_nodes);

        const int n_tiles = (n_nodes + 15) / 16;
        const int gemm_blocks = (n_tiles + 3) / 4;
        agg_gemm_kernel<<<gemm_blocks, 256, 0, stream>>>(Agg, W, out, n_nodes);
    } else {
        fused_kernel<<<2048, 256, 0, stream>>>(X, W, rp, ci, out, n_nodes);
    }
}

// Round 9
// 147.268 us; speedup vs baseline: 1.0091x; 1.0091x over previous
//
#include <hip/hip_runtime.h>
#include <cstdint>
#include <cstddef>

#define D 64

typedef float    f32x4 __attribute__((ext_vector_type(4)));
typedef float    f32x2 __attribute__((ext_vector_type(2)));
typedef short    s16x8 __attribute__((ext_vector_type(8)));
typedef uint32_t u32x4 __attribute__((ext_vector_type(4)));

// round-to-nearest-even fp32 -> bf16 (bits in low 16)
__device__ __forceinline__ uint32_t rne_bf16(float f) {
    uint32_t x = __float_as_uint(f);
    return (x + 0x7fffu + ((x >> 16) & 1u)) >> 16;
}
__device__ __forceinline__ float bf16lo(uint32_t u) { return __uint_as_float(u << 16); }
__device__ __forceinline__ float bf16hi(uint32_t u) { return __uint_as_float(u & 0xffff0000u); }

// Kernel 1: Xh = packed bf16(X). u32 t of a row packs features (2t, 2t+1).
__global__ __launch_bounds__(256) void cast_kernel(
    const float* __restrict__ X, uint32_t* __restrict__ Xh, long n4)
{
    long i = (long)blockIdx.x * blockDim.x + threadIdx.x;
    const long stride = (long)gridDim.x * blockDim.x;
    for (; i < n4; i += stride) {
        f32x4 v = __builtin_nontemporal_load((const f32x4*)X + i);
        uint2 o;
        o.x = rne_bf16(v.x) | (rne_bf16(v.y) << 16);
        o.y = rne_bf16(v.z) | (rne_bf16(v.w) << 16);
        ((uint2*)Xh)[i] = o;
    }
}

__device__ __forceinline__ void acc_row(f32x2 acc[4], const u32x4 u) {
#pragma unroll
    for (int k = 0; k < 4; ++k) {
        f32x2 v;
        v.x = bf16lo(u[k]);
        v.y = bf16hi(u[k]);
        acc[k] += v;          // v_pk_add_f32
    }
}

// Kernel 2: Agg[r] = bf16( sum_{e in row r} Xh[ci[e]] ).
// One row per wave ITERATION, grid-strided (~12 rows/wave), with a 2-deep
// cross-row software pipeline: while row k's gathers are in flight we issue
// row k+1's index loads and row k+2's row-pointer loads. o = lane>>3 (edge
// slot 0..7), p = lane&7 (feature octet: uint4 = 8 bf16 = full 128B row per
// 8 lanes). Fast path covers deg<=32 (~87% of rows); longer rows take the
// R7-style ladder for edges beyond 32.
__global__ __launch_bounds__(256) void gather5_kernel(
    const uint32_t* __restrict__ Xh, const int* __restrict__ rp,
    const int* __restrict__ ci, uint32_t* __restrict__ Agg, int n_nodes)
{
    const int lane = threadIdx.x & 63;
    const int o = lane >> 3;
    const int p = lane & 7;
    const int gw = (int)((blockIdx.x * blockDim.x + threadIdx.x) >> 6);
    const int nw = (int)((gridDim.x * blockDim.x) >> 6);

    int rowC = gw;
    if (rowC >= n_nodes) return;

    // prologue: rp + idx for rowC; rp for rowN
    int e0C = rp[rowC];
    int e1C = rp[rowC + 1];
    int i0C, i1C, i2C, i3C;
    {
        const int hi = e1C - 1;
        i0C = ci[max(min(e0C + 0  + o, hi), 0)];
        i1C = ci[max(min(e0C + 8  + o, hi), 0)];
        i2C = ci[max(min(e0C + 16 + o, hi), 0)];
        i3C = ci[max(min(e0C + 24 + o, hi), 0)];
    }
    int rowN = rowC + nw;
    bool hasN = rowN < n_nodes;
    int e0N = 0, e1N = 0;
    if (hasN) { e0N = rp[rowN]; e1N = rp[rowN + 1]; }

    for (;;) {
        // 1) issue NEXT row's idx loads (overlaps current row's gathers)
        int i0N, i1N, i2N, i3N;
        if (hasN) {
            const int hi = e1N - 1;
            i0N = ci[max(min(e0N + 0  + o, hi), 0)];
            i1N = ci[max(min(e0N + 8  + o, hi), 0)];
            i2N = ci[max(min(e0N + 16 + o, hi), 0)];
            i3N = ci[max(min(e0N + 24 + o, hi), 0)];
        }
        // 2) prefetch rp for row after next
        const int rowN2 = rowN + nw;
        const bool hasN2 = hasN && (rowN2 < n_nodes);
        int e0N2 = 0, e1N2 = 0;
        if (hasN2) { e0N2 = rp[rowN2]; e1N2 = rp[rowN2 + 1]; }

        // 3) gather current row's first 32 edges (exec-predicated)
        const int deg = e1C - e0C;
        u32x4 u0 = {0,0,0,0}, u1 = {0,0,0,0}, u2 = {0,0,0,0}, u3 = {0,0,0,0};
        if (o < deg)      u0 = *(const u32x4*)(Xh + (size_t)i0C * 32 + p * 4);
        if (o + 8 < deg)  u1 = *(const u32x4*)(Xh + (size_t)i1C * 32 + p * 4);
        if (o + 16 < deg) u2 = *(const u32x4*)(Xh + (size_t)i2C * 32 + p * 4);
        if (o + 24 < deg) u3 = *(const u32x4*)(Xh + (size_t)i3C * 32 + p * 4);

        f32x2 acc[4] = {{0.f,0.f},{0.f,0.f},{0.f,0.f},{0.f,0.f}};
        acc_row(acc, u0); acc_row(acc, u1); acc_row(acc, u2); acc_row(acc, u3);

        // 4) slow path: edges 32.. (wave-uniform branch, ~13% of rows)
        if (deg > 32) {
            int e = e0C + 32;
            for (; e + 32 <= e1C; e += 32) {
                const int j0 = ci[e + o];
                const int j1 = ci[e + 8 + o];
                const int j2 = ci[e + 16 + o];
                const int j3 = ci[e + 24 + o];
                const u32x4 v0 = *(const u32x4*)(Xh + (size_t)j0 * 32 + p * 4);
                const u32x4 v1 = *(const u32x4*)(Xh + (size_t)j1 * 32 + p * 4);
                const u32x4 v2 = *(const u32x4*)(Xh + (size_t)j2 * 32 + p * 4);
                const u32x4 v3 = *(const u32x4*)(Xh + (size_t)j3 * 32 + p * 4);
                acc_row(acc, v0); acc_row(acc, v1);
                acc_row(acc, v2); acc_row(acc, v3);
            }
            const int rem = e1C - e;  // 0..31
            if (rem > 0) {
                const int hi = e1C - 1;
                const int j0 = ci[min(e + o, hi)];
                const int j1 = ci[min(e + 8 + o, hi)];
                const int j2 = ci[min(e + 16 + o, hi)];
                const int j3 = ci[min(e + 24 + o, hi)];
                u32x4 v0 = {0,0,0,0}, v1 = {0,0,0,0}, v2 = {0,0,0,0}, v3 = {0,0,0,0};
                if (o < rem)      v0 = *(const u32x4*)(Xh + (size_t)j0 * 32 + p * 4);
                if (o + 8 < rem)  v1 = *(const u32x4*)(Xh + (size_t)j1 * 32 + p * 4);
                if (o + 16 < rem) v2 = *(const u32x4*)(Xh + (size_t)j2 * 32 + p * 4);
                if (o + 24 < rem) v3 = *(const u32x4*)(Xh + (size_t)j3 * 32 + p * 4);
                acc_row(acc, v0); acc_row(acc, v1);
                acc_row(acc, v2); acc_row(acc, v3);
            }
        }

        // 5) reduce across the 8 edge slots; lanes 0..7 hold full sums
#pragma unroll
        for (int k = 0; k < 4; ++k) {
            f32x2 v = acc[k];
            v.x += __shfl_xor(v.x, 8, 64);  v.y += __shfl_xor(v.y, 8, 64);
            v.x += __shfl_xor(v.x, 16, 64); v.y += __shfl_xor(v.y, 16, 64);
            v.x += __shfl_xor(v.x, 32, 64); v.y += __shfl_xor(v.y, 32, 64);
            acc[k] = v;
        }
        if (lane < 8) {
            u32x4 w;
#pragma unroll
            for (int k = 0; k < 4; ++k)
                w[k] = rne_bf16(acc[k].x) | (rne_bf16(acc[k].y) << 16);
            *(u32x4*)(Agg + (size_t)rowC * 32 + p * 4) = w;  // 8x16B = 128B
        }

        if (!hasN) break;
        // 6) rotate pipeline state
        rowC = rowN; e0C = e0N; e1C = e1N;
        i0C = i0N; i1C = i1N; i2C = i2N; i3C = i3N;
        rowN = rowN2; hasN = hasN2; e0N = e0N2; e1N = e1N2;
    }
}

// Kernel 3: out = Agg(bf16) @ W via mfma_f32_16x16x32_bf16.
// One wave per 16-row tile (grid-strided). B-frags (W) in VGPRs per wave.
__global__ __launch_bounds__(256) void agg_gemm_kernel(
    const uint32_t* __restrict__ Agg, const float* __restrict__ W,
    float* __restrict__ out, int n_nodes)
{
    const int lane = threadIdx.x & 63;
    const int n = lane & 15;
    const int q = lane >> 4;

    s16x8 Bf[4][2];
#pragma unroll
    for (int c = 0; c < 4; ++c)
#pragma unroll
        for (int kb = 0; kb < 2; ++kb) {
            s16x8 bfr;
#pragma unroll
            for (int j = 0; j < 8; ++j) {
                const int k = kb * 32 + q * 8 + j;
                bfr[j] = (short)rne_bf16(W[k * D + c * 16 + n]);
            }
            Bf[c][kb] = bfr;
        }

    const int n_tiles = (n_nodes + 15) / 16;
    const int gwave = (int)((blockIdx.x * blockDim.x + threadIdx.x) >> 6);
    const int nwaves = (int)((gridDim.x * blockDim.x) >> 6);

    for (int t = gwave; t < n_tiles; t += nwaves) {
        const int m0 = t * 16;
        int arow = m0 + n;
        if (arow >= n_nodes) arow = n_nodes - 1;  // clamp (tail tile)
        const s16x8 A0 = *(const s16x8*)(Agg + (size_t)arow * 32 + q * 4);
        const s16x8 A1 = *(const s16x8*)(Agg + (size_t)arow * 32 + 16 + q * 4);

        f32x4 acc[4];
#pragma unroll
        for (int c = 0; c < 4; ++c) {
            f32x4 z = {0.f, 0.f, 0.f, 0.f};
            z = __builtin_amdgcn_mfma_f32_16x16x32_bf16(A0, Bf[c][0], z, 0, 0, 0);
            z = __builtin_amdgcn_mfma_f32_16x16x32_bf16(A1, Bf[c][1], z, 0, 0, 0);
            acc[c] = z;
        }
#pragma unroll
        for (int r = 0; r < 4; ++r) {
            const int ro = m0 + q * 4 + r;
            if (ro < n_nodes) {
#pragma unroll
                for (int c = 0; c < 4; ++c)
                    out[(size_t)ro * D + c * 16 + n] = acc[c][r];
            }
        }
    }
}

// Fallback if ws can't hold Xh+Agg: fused per-row aggregate + shfl GEMM.
__global__ __launch_bounds__(256) void fused_kernel(
    const float* __restrict__ X, const float* __restrict__ W,
    const int* __restrict__ rp, const int* __restrict__ ci,
    float* __restrict__ out, int n_nodes)
{
    __shared__ float Wl[D * D];
    for (int i = threadIdx.x; i < D * D; i += 256) Wl[i] = W[i];
    __syncthreads();

    const int lane = threadIdx.x & 63;
    const int gwave = (int)((blockIdx.x * blockDim.x + threadIdx.x) >> 6);
    const int nwaves = (int)((gridDim.x * blockDim.x) >> 6);

    for (int row = gwave; row < n_nodes; row += nwaves) {
        int e0 = rp[row];
        int e1 = rp[row + 1];
        float acc = 0.f;
        for (int e = e0; e < e1; ++e) acc += X[ci[e] * D + lane];
        float sum = 0.f;
#pragma unroll
        for (int d = 0; d < D; ++d) {
            float a = __shfl(acc, d, 64);
            sum += a * Wl[d * D + lane];
        }
        out[row * D + lane] = sum;
    }
}

extern "C" void kernel_launch(void* const* d_in, const int* in_sizes, int n_in,
                              void* d_out, int out_size, void* d_ws, size_t ws_size,
                              hipStream_t stream)
{
    const float* X  = (const float*)d_in[0];   // [n, 64]
    const float* W  = (const float*)d_in[1];   // [64, 64]
    const int*   rp = (const int*)d_in[2];     // [n+1]
    const int*   ci = (const int*)d_in[3];     // [n_edges]
    float* out = (float*)d_out;

    const int n_nodes = in_sizes[2] - 1;
    const size_t row_bytes = 32 * sizeof(uint32_t);           // 128 B bf16 row
    const size_t need = 2 * (size_t)n_nodes * row_bytes;      // Xh + Agg

    if (ws_size >= need) {
        uint32_t* Xh  = (uint32_t*)d_ws;
        uint32_t* Agg = (uint32_t*)((char*)d_ws + (size_t)n_nodes * row_bytes);

        const long n4 = (long)n_nodes * (D / 4);
        int cast_blocks = (int)((n4 + 255) / 256);
        if (cast_blocks > 6400) cast_blocks = 6400;
        cast_kernel<<<cast_blocks, 256, 0, stream>>>(X, Xh, n4);

        // 2048 blocks = 8 blocks/CU resident; each wave pipelines ~12 rows.
        gather5_kernel<<<2048, 256, 0, stream>>>(Xh, rp, ci, Agg, n_nodes);

        const int n_tiles = (n_nodes + 15) / 16;
        const int gemm_blocks = (n_tiles + 3) / 4;
        agg_gemm_kernel<<<gemm_blocks, 256, 0, stream>>>(Agg, W, out, n_nodes);
    } else {
        fused_kernel<<<2048, 256, 0, stream>>>(X, W, rp, ci, out, n_nodes);
    }
}